// Round 7
// baseline (293.517 us; speedup 1.0000x reference)
//
#include <hip/hip_runtime.h>
#include <hip/hip_bf16.h>
#include <stdint.h>

// MoE top-2 of 8 experts.  B=2,T=1024 -> nt=2048 tokens, D=1024, H=4096, E=8.
// d_out layout: out[2*1024*1024] f32 | gate_value[2048*8] f32 | lb_loss[1] f32.
//
// R7: conv passes ELIMINATED (~70us).  GEMMs read f32 weights directly:
// B side = coalesced global_load_dwordx4 -> v_cvt_pk_bf16_f32 -> swizzled
// ds_write_b64 (issue-early/write-late, T14); A side = global_load_lds bf16.
// Double-buffered LDS (32KB), one __syncthreads per K-step.  Fragment-read
// XOR swizzle kept from R5 (measured 0 bank conflicts).

#define NTOK 2048
#define DDIM 1024
#define HDIM 4096
#define NEXP 8
#define KSPLIT 2

typedef float  f32x4  __attribute__((ext_vector_type(4)));
typedef __bf16 bf16x8 __attribute__((ext_vector_type(8)));
typedef __bf16 bf16x4 __attribute__((ext_vector_type(4)));

typedef const __attribute__((address_space(1))) void g1_t;
typedef __attribute__((address_space(3))) void l3_t;
__device__ __forceinline__ void gld16(const void* g, void* l) {
  // async global->LDS, 16B/lane; LDS dest = wave-uniform base + lane*16
  __builtin_amdgcn_global_load_lds((g1_t*)g, (l3_t*)l, 16, 0, 0);
}

// ---------------- init: zero the fill counters ----------------
__global__ void init_kernel(int* fill) {
  int t = threadIdx.x;
  if (t < NEXP) fill[t] = 0;
}

// ---------------- zero ybuf (gemm2 accumulates with atomics) ----------------
__global__ __launch_bounds__(256)
void zero_y_kernel(float* __restrict__ y) {
  size_t i = (size_t)blockIdx.x * 256 + threadIdx.x;
  ((f32x4*)y)[i] = (f32x4){0.f, 0.f, 0.f, 0.f};
}

// ---------------- gate: logits, softmax, top2; emits xbf.  NO atomics. ----------------
__global__ __launch_bounds__(256)
void gate_kernel(const float* __restrict__ x, const unsigned char* __restrict__ pmask,
                 const float* __restrict__ Wg, float* __restrict__ gate_out,
                 int* __restrict__ tix, float* __restrict__ twt,
                 __bf16* __restrict__ xbf)
{
  int wave = threadIdx.x >> 6, lane = threadIdx.x & 63;
  int t = blockIdx.x * 4 + wave;   // one wave per token
  const f32x4* x4 = (const f32x4*)(x + (size_t)t * DDIM);
  const f32x4* w4 = (const f32x4*)Wg;
  bf16x4* xb4 = (bf16x4*)(xbf + (size_t)t * DDIM);
  float acc[NEXP];
#pragma unroll
  for (int e = 0; e < NEXP; ++e) acc[e] = 0.f;
#pragma unroll
  for (int i = 0; i < 4; ++i) {
    f32x4 xv = x4[i * 64 + lane];
    bf16x4 xo;
#pragma unroll
    for (int q = 0; q < 4; ++q) xo[q] = (__bf16)xv[q];
    xb4[i * 64 + lane] = xo;
#pragma unroll
    for (int e = 0; e < NEXP; ++e) {
      f32x4 wv = w4[e * 256 + i * 64 + lane];
      acc[e] += xv[0]*wv[0] + xv[1]*wv[1] + xv[2]*wv[2] + xv[3]*wv[3];
    }
  }
#pragma unroll
  for (int e = 0; e < NEXP; ++e) {
    float v = acc[e];
#pragma unroll
    for (int off = 32; off > 0; off >>= 1) v += __shfl_xor(v, off, 64);
    acc[e] = v;
  }
  if (lane == 0) {
    bool pm = pmask[t] != 0;
    float m = acc[0];
#pragma unroll
    for (int e = 1; e < NEXP; ++e) m = fmaxf(m, acc[e]);
    float g[NEXP]; float s = 0.f;
#pragma unroll
    for (int e = 0; e < NEXP; ++e) { g[e] = expf(acc[e] - m); s += g[e]; }
    float inv = 1.f / s;
#pragma unroll
    for (int e = 0; e < NEXP; ++e) g[e] *= inv;
    if (pm) {
#pragma unroll
      for (int e = 0; e < NEXP; ++e) g[e] = 0.f;
    }
    int i1 = 0;
#pragma unroll
    for (int e = 1; e < NEXP; ++e) if (g[e] > g[i1]) i1 = e;
    int i2 = -1;
#pragma unroll
    for (int e = 0; e < NEXP; ++e) if (e != i1 && (i2 < 0 || g[e] > g[i2])) i2 = e;
    float w1 = g[i1], w2 = g[i2], ss = w1 + w2;
    if (ss == 0.f) ss = 1.f;
    w1 /= ss; w2 /= ss;
#pragma unroll
    for (int e = 0; e < NEXP; ++e) gate_out[(size_t)t * NEXP + e] = g[e];
    tix[2*t] = i1; tix[2*t+1] = i2;
    twt[2*t] = w1; twt[2*t+1] = w2;
  }
}

// ---------------- stats: single-block tree reduce -> ecount/offs/lb ----------------
__global__ __launch_bounds__(1024)
void stats_kernel(const float* __restrict__ gate_out, const int* __restrict__ tix,
                  const unsigned char* __restrict__ pmask,
                  int* __restrict__ ecount, int* __restrict__ offs,
                  float* __restrict__ lb_out)
{
  int tid = threadIdx.x, lane = tid & 63, wv = tid >> 6;   // 16 waves
  float lg[NEXP]; float lt1[NEXP]; int lec[NEXP]; float ln = 0.f;
#pragma unroll
  for (int e = 0; e < NEXP; ++e) { lg[e] = 0.f; lt1[e] = 0.f; lec[e] = 0; }
#pragma unroll
  for (int it = 0; it < NTOK / 1024; ++it) {
    int t = tid + it * 1024;
    f32x4 g0 = ((const f32x4*)(gate_out + (size_t)t * NEXP))[0];
    f32x4 g1 = ((const f32x4*)(gate_out + (size_t)t * NEXP))[1];
    lg[0] += g0[0]; lg[1] += g0[1]; lg[2] += g0[2]; lg[3] += g0[3];
    lg[4] += g1[0]; lg[5] += g1[1]; lg[6] += g1[2]; lg[7] += g1[3];
    if (!pmask[t]) {
      int i1 = tix[2*t], i2 = tix[2*t+1];
      lt1[i1] += 1.f; lec[i1] += 1; lec[i2] += 1; ln += 1.f;
    }
  }
#pragma unroll
  for (int e = 0; e < NEXP; ++e) {
#pragma unroll
    for (int off = 32; off > 0; off >>= 1) {
      lg[e]  += __shfl_xor(lg[e],  off, 64);
      lt1[e] += __shfl_xor(lt1[e], off, 64);
      lec[e] += __shfl_xor(lec[e], off, 64);
    }
  }
#pragma unroll
  for (int off = 32; off > 0; off >>= 1) ln += __shfl_xor(ln, off, 64);
  __shared__ float sg[16][NEXP], st[16][NEXP], sn[16];
  __shared__ int   se[16][NEXP];
  if (lane == 0) {
#pragma unroll
    for (int e = 0; e < NEXP; ++e) { sg[wv][e] = lg[e]; st[wv][e] = lt1[e]; se[wv][e] = lec[e]; }
    sn[wv] = ln;
  }
  __syncthreads();
  if (tid == 0) {
    float G[NEXP] = {0}, T1[NEXP] = {0}; int EC[NEXP] = {0}; float N = 0.f;
    for (int w = 0; w < 16; ++w) {
      N += sn[w];
#pragma unroll
      for (int e = 0; e < NEXP; ++e) { G[e] += sg[w][e]; T1[e] += st[w][e]; EC[e] += se[w][e]; }
    }
    int o = 0;
    for (int e = 0; e < NEXP; ++e) { ecount[e] = EC[e]; offs[e] = o; o += EC[e]; }
    if (N <= 0.f) N = 1.f;
    float lb = 0.f;
    for (int e = 0; e < NEXP; ++e) lb += (T1[e] / N) * (G[e] / N);
    lb_out[0] = (float)NEXP * lb;
  }
}

// ---------------- compaction: ballot-aggregated (1 atomic/wave/expert) ----------------
__global__ __launch_bounds__(256)
void compact_kernel(const unsigned char* __restrict__ pmask, const int* __restrict__ tix,
                    const int* __restrict__ offs, int* __restrict__ fill,
                    int* __restrict__ tok_list, int* __restrict__ slot_of)
{
  int t = blockIdx.x * 256 + threadIdx.x;
  int lane = threadIdx.x & 63;
  bool pm = pmask[t] != 0;
#pragma unroll
  for (int j = 0; j < 2; ++j) {
    int e = pm ? -1 : tix[2*t + j];
    int pos = -1;
#pragma unroll
    for (int ex = 0; ex < NEXP; ++ex) {
      unsigned long long mask = __ballot(e == ex);
      if (mask) {
        int leader = (int)(__ffsll((long long)mask) - 1);
        int base = 0;
        if (lane == leader) base = atomicAdd(&fill[ex], (int)__popcll(mask));
        base = __shfl(base, leader, 64);
        if (e == ex)
          pos = offs[ex] + base + (int)__popcll(mask & ((1ull << lane) - 1ull));
      }
    }
    if (e >= 0) { tok_list[pos] = t; slot_of[2*t + j] = pos; }
    else slot_of[2*t + j] = -1;
  }
}

// ======================= GEMM cores (R7) =======================
// 128x128 tile, BK=32, dbuf LDS (32KB), 4 waves (2x2), mfma 16x16x32 bf16.
// A (bf16): global_load_lds, linear dest, source pre-swizzled.
// B (f32 weights): global_load_dwordx4 (coalesced) -> cvt_pk bf16 ->
//   swizzled ds_write_b64.  Loads for tile t+1 issued BEFORE MFMA(t);
//   B regs consumed (cvt+write) after.  One __syncthreads per K-step.
// Swizzle: LDS 16B-chunk cs of row r holds data chunk cd = cs ^ ((r>>1)&3).
// Fragment read undoes it: cg = ((lane>>4) ^ ((lane>>1)&3))*8 elems.
//
// B thread map: q=0..3: row r=(tid>>3)+32q, 8B half-chunk (tid&7):
//   data cd=(tid&7)>>1, h=tid&1 -> LDS elem r*32 + (cd^((r>>1)&3))*8 + h*4.

#define B_STAGE_LOAD(breg, bp, koff)                                   \
  _Pragma("unroll")                                                    \
  for (int q = 0; q < 4; ++q) breg[q] = *(const f32x4*)(bp[q] + (koff));

#define B_STAGE_WRITE(dstBs, breg)                                     \
  _Pragma("unroll")                                                    \
  for (int q = 0; q < 4; ++q) {                                        \
    bf16x4 o;                                                          \
    o[0] = (__bf16)breg[q][0]; o[1] = (__bf16)breg[q][1];              \
    o[2] = (__bf16)breg[q][2]; o[3] = (__bf16)breg[q][3];              \
    *(bf16x4*)&(dstBs)[bwofs[q]] = o;                                  \
  }

// ---------------- GEMM1: h[slot,:] = relu(xbf[tok]·W1[e]^T + b1[e]) ----------------
__global__ __launch_bounds__(256)
void gemm1_kernel(const __bf16* __restrict__ xbf, const float* __restrict__ W1,
                  const float* __restrict__ b1, const int* __restrict__ ecount,
                  const int* __restrict__ offs, const int* __restrict__ tok_list,
                  __bf16* __restrict__ hbuf)
{
  const int NTILE = HDIM / 128;   // 32
  const int MTILE = NTOK / 128;   // 16
  int bid = blockIdx.x;
  int e = bid / (MTILE * NTILE);
  int rem = bid % (MTILE * NTILE);
  int mt = rem / NTILE, nt = rem % NTILE;
  int cnt = ecount[e];
  if (mt * 128 >= cnt) return;
  int off = offs[e];

  __shared__ __bf16 As[2][128 * 32];
  __shared__ __bf16 Bs[2][128 * 32];

  int tid = threadIdx.x, lane = tid & 63, wave = tid >> 6;
  int wm = wave >> 1, wn = wave & 1;

  // A staging (bf16 tokens, gld16): 2 calls, rows c*64+(tid>>2), chunk swizzled on src
  const __bf16* aP[2];
#pragma unroll
  for (int c = 0; c < 2; ++c) {
    int row = c * 64 + (tid >> 2);
    int cd = (tid & 3) ^ ((row >> 1) & 3);
    int mrow = mt * 128 + row;
    int tok = tok_list[off + ((mrow < cnt) ? mrow : 0)];
    aP[c] = xbf + (size_t)tok * DDIM + cd * 8;
  }
  // B staging (f32 weights): 4 rows/thread
  const float* bp[4];
  int bwofs[4];
#pragma unroll
  for (int q = 0; q < 4; ++q) {
    int r = (tid >> 3) + 32 * q;
    bp[q] = W1 + (size_t)e * HDIM * DDIM + (size_t)(nt * 128 + r) * DDIM + (tid & 7) * 4;
    int cd = (tid & 7) >> 1, h = tid & 1;
    bwofs[q] = r * 32 + ((cd ^ ((r >> 1) & 3)) << 3) + h * 4;
  }
  int cg = ((lane >> 4) ^ ((lane >> 1) & 3)) << 3;

  f32x4 acc[4][4];
#pragma unroll
  for (int m = 0; m < 4; ++m)
#pragma unroll
    for (int n = 0; n < 4; ++n) acc[m][n] = (f32x4){0.f, 0.f, 0.f, 0.f};

  const int NIT = DDIM / 32;   // 32
  f32x4 breg[4];
  // prologue: tile 0
#pragma unroll
  for (int c = 0; c < 2; ++c) gld16(aP[c], &As[0][(c * 64 + wave * 16) * 32]);
  B_STAGE_LOAD(breg, bp, 0)
  B_STAGE_WRITE(Bs[0], breg)
  __syncthreads();

  for (int it = 0; it < NIT; ++it) {
    int cur = it & 1, nxt = cur ^ 1;
    if (it + 1 < NIT) {
      int k0 = (it + 1) * 32;
#pragma unroll
      for (int c = 0; c < 2; ++c) gld16(aP[c] + k0, &As[nxt][(c * 64 + wave * 16) * 32]);
      B_STAGE_LOAD(breg, bp, k0)
    }
    bf16x8 af[4], bfr[4];
#pragma unroll
    for (int m = 0; m < 4; ++m) af[m]  = *(const bf16x8*)&As[cur][(wm*64 + m*16 + (lane & 15)) * 32 + cg];
#pragma unroll
    for (int n = 0; n < 4; ++n) bfr[n] = *(const bf16x8*)&Bs[cur][(wn*64 + n*16 + (lane & 15)) * 32 + cg];
#pragma unroll
    for (int m = 0; m < 4; ++m)
#pragma unroll
      for (int n = 0; n < 4; ++n)
        acc[m][n] = __builtin_amdgcn_mfma_f32_16x16x32_bf16(af[m], bfr[n], acc[m][n], 0, 0, 0);
    if (it + 1 < NIT) { B_STAGE_WRITE(Bs[nxt], breg) }
    __syncthreads();   // drains vmcnt (A gld_lds) + lgkmcnt (B writes)
  }

  // epilogue: +bias, relu, bf16 store
#pragma unroll
  for (int n = 0; n < 4; ++n) {
    int col = nt * 128 + wn * 64 + n * 16 + (lane & 15);
    float bias = b1[e * HDIM + col];
#pragma unroll
    for (int m = 0; m < 4; ++m) {
#pragma unroll
      for (int j = 0; j < 4; ++j) {
        int mr = mt * 128 + wm * 64 + m * 16 + ((lane >> 4) << 2) + j;
        if (mr < cnt) {
          float v = fmaxf(acc[m][n][j] + bias, 0.f);
          hbuf[(size_t)(off + mr) * HDIM + col] = (__bf16)v;
        }
      }
    }
  }
}

// ---------------- GEMM2 (K-split): ybuf[slot,:] += hbuf[slot]·W2[e]^T ----------------
__global__ __launch_bounds__(256)
void gemm2_kernel(const __bf16* __restrict__ hbuf, const float* __restrict__ W2,
                  const int* __restrict__ ecount, const int* __restrict__ offs,
                  float* __restrict__ ybuf)
{
  const int NTILE = DDIM / 128;   // 8
  const int MTILE = NTOK / 128;   // 16
  int bid = blockIdx.x;
  int e = bid / (MTILE * NTILE * KSPLIT);
  int rem = bid % (MTILE * NTILE * KSPLIT);
  int mt = rem / (NTILE * KSPLIT);
  int rem2 = rem % (NTILE * KSPLIT);
  int nt = rem2 / KSPLIT, kc = rem2 % KSPLIT;
  int cnt = ecount[e];
  if (mt * 128 >= cnt) return;
  int off = offs[e];

  __shared__ __bf16 As[2][128 * 32];
  __shared__ __bf16 Bs[2][128 * 32];

  int tid = threadIdx.x, lane = tid & 63, wave = tid >> 6;
  int wm = wave >> 1, wn = wave & 1;

  const __bf16* aP[2];
#pragma unroll
  for (int c = 0; c < 2; ++c) {
    int row = c * 64 + (tid >> 2);
    int cd = (tid & 3) ^ ((row >> 1) & 3);
    aP[c] = hbuf + (size_t)(off + mt * 128 + row) * HDIM + cd * 8;
  }
  const float* bp[4];
  int bwofs[4];
#pragma unroll
  for (int q = 0; q < 4; ++q) {
    int r = (tid >> 3) + 32 * q;
    bp[q] = W2 + (size_t)e * DDIM * HDIM + (size_t)(nt * 128 + r) * HDIM + (tid & 7) * 4;
    int cd = (tid & 7) >> 1, h = tid & 1;
    bwofs[q] = r * 32 + ((cd ^ ((r >> 1) & 3)) << 3) + h * 4;
  }
  int cg = ((lane >> 4) ^ ((lane >> 1) & 3)) << 3;

  f32x4 acc[4][4];
#pragma unroll
  for (int m = 0; m < 4; ++m)
#pragma unroll
    for (int n = 0; n < 4; ++n) acc[m][n] = (f32x4){0.f, 0.f, 0.f, 0.f};

  const int KCH = HDIM / KSPLIT;      // 2048
  const int NIT = KCH / 32;           // 64
  int kbeg = kc * KCH;
  f32x4 breg[4];
#pragma unroll
  for (int c = 0; c < 2; ++c) gld16(aP[c] + kbeg, &As[0][(c * 64 + wave * 16) * 32]);
  B_STAGE_LOAD(breg, bp, kbeg)
  B_STAGE_WRITE(Bs[0], breg)
  __syncthreads();

  for (int it = 0; it < NIT; ++it) {
    int cur = it & 1, nxt = cur ^ 1;
    if (it + 1 < NIT) {
      int k0 = kbeg + (it + 1) * 32;
#pragma unroll
      for (int c = 0; c < 2; ++c) gld16(aP[c] + k0, &As[nxt][(c * 64 + wave * 16) * 32]);
      B_STAGE_LOAD(breg, bp, k0)
    }
    bf16x8 af[4], bfr[4];
#pragma unroll
    for (int m = 0; m < 4; ++m) af[m]  = *(const bf16x8*)&As[cur][(wm*64 + m*16 + (lane & 15)) * 32 + cg];
#pragma unroll
    for (int n = 0; n < 4; ++n) bfr[n] = *(const bf16x8*)&Bs[cur][(wn*64 + n*16 + (lane & 15)) * 32 + cg];
#pragma unroll
    for (int m = 0; m < 4; ++m)
#pragma unroll
      for (int n = 0; n < 4; ++n)
        acc[m][n] = __builtin_amdgcn_mfma_f32_16x16x32_bf16(af[m], bfr[n], acc[m][n], 0, 0, 0);
    if (it + 1 < NIT) { B_STAGE_WRITE(Bs[nxt], breg) }
    __syncthreads();
  }

  // epilogue: atomic accumulate raw partials (bias+gate weight in combine)
#pragma unroll
  for (int m = 0; m < 4; ++m) {
#pragma unroll
    for (int j = 0; j < 4; ++j) {
      int mr = mt * 128 + wm * 64 + m * 16 + ((lane >> 4) << 2) + j;
      if (mr >= cnt) continue;
      int slot = off + mr;
#pragma unroll
      for (int n = 0; n < 4; ++n) {
        int col = nt * 128 + wn * 64 + n * 16 + (lane & 15);
        atomicAdd(&ybuf[(size_t)slot * DDIM + col], acc[m][n][j]);
      }
    }
  }
}

// ---------------- combine: out[t] = wA*(y[sA]+b2[eA]) + wB*(y[sB]+b2[eB]) ----------------
__global__ __launch_bounds__(256)
void combine_kernel(const float* __restrict__ ybuf, const int* __restrict__ slot_of,
                    const int* __restrict__ tix, const float* __restrict__ twt,
                    const float* __restrict__ b2, float* __restrict__ out)
{
  int t = blockIdx.x;
  int d4 = threadIdx.x;
  int sA = slot_of[2*t], sB = slot_of[2*t + 1];
  f32x4 r = (f32x4){0.f, 0.f, 0.f, 0.f};
  if (sA >= 0) {
    float wA = twt[2*t];
    f32x4 y = ((const f32x4*)(ybuf + (size_t)sA * DDIM))[d4];
    f32x4 b = ((const f32x4*)(b2 + (size_t)tix[2*t] * DDIM))[d4];
    r += wA * (y + b);
  }
  if (sB >= 0) {
    float wB = twt[2*t + 1];
    f32x4 y = ((const f32x4*)(ybuf + (size_t)sB * DDIM))[d4];
    f32x4 b = ((const f32x4*)(b2 + (size_t)tix[2*t + 1] * DDIM))[d4];
    r += wB * (y + b);
  }
  ((f32x4*)(out + (size_t)t * DDIM))[d4] = r;
}

extern "C" void kernel_launch(void* const* d_in, const int* in_sizes, int n_in,
                              void* d_out, int out_size, void* d_ws, size_t ws_size,
                              hipStream_t stream)
{
  const float* x  = (const float*)d_in[0];
  const unsigned char* pm = (const unsigned char*)d_in[1];
  const float* Wg = (const float*)d_in[2];
  const float* W1 = (const float*)d_in[3];
  const float* b1 = (const float*)d_in[4];
  const float* W2 = (const float*)d_in[5];
  const float* b2 = (const float*)d_in[6];
  float* out = (float*)d_out;
  float* gate_out = out + (size_t)NTOK * DDIM;        // 2097152
  float* lb_out = gate_out + (size_t)NTOK * NEXP;     // 2113536

  char* w = (char*)d_ws;
  int*   ecount   = (int*)(w + 0);
  int*   offs     = (int*)(w + 64);
  int*   fill     = (int*)(w + 128);
  int*   tix      = (int*)(w + 512);                       // 16 KB
  float* twt      = (float*)(w + 512 + 16384);             // 16 KB
  int*   tok_list = (int*)(w + 512 + 32768);               // 16 KB
  int*   slot_of  = (int*)(w + 512 + 49152);               // 16 KB
  uintptr_t p = ((uintptr_t)(w + 512 + 65536) + 255) & ~(uintptr_t)255;
  __bf16* xbf  = (__bf16*)p;                                    // 4 MB
  p += (size_t)NTOK * DDIM * 2;
  __bf16* hbuf = (__bf16*)p;                                    // 33 MB
  p += (size_t)(2 * NTOK + 128) * HDIM * 2;
  float*  ybuf = (float*)p;                                     // 16 MB

  init_kernel<<<1, 64, 0, stream>>>(fill);
  zero_y_kernel<<<(2 * NTOK * DDIM / 4) / 256, 256, 0, stream>>>(ybuf);
  gate_kernel<<<NTOK / 4, 256, 0, stream>>>(x, pm, Wg, gate_out, tix, twt, xbf);
  stats_kernel<<<1, 1024, 0, stream>>>(gate_out, tix, pm, ecount, offs, lb_out);
  compact_kernel<<<NTOK / 256, 256, 0, stream>>>(pm, tix, offs, fill, tok_list, slot_of);
  gemm1_kernel<<<NEXP * (NTOK / 128) * (HDIM / 128), 256, 0, stream>>>(xbf, W1, b1, ecount, offs, tok_list, hbuf);
  gemm2_kernel<<<NEXP * (NTOK / 128) * (DDIM / 128) * KSPLIT, 256, 0, stream>>>(hbuf, W2, ecount, offs, ybuf);
  combine_kernel<<<NTOK, 256, 0, stream>>>(ybuf, slot_of, tix, twt, b2, out);
}